// Round 3
// baseline (195.757 us; speedup 1.0000x reference)
//
#include <hip/hip_runtime.h>
#include <math.h>

#define NB 32
#define NA 5
#define NC 80
#define NH 38
#define NW 38
#define MAXT 50
#define CELLS (NH * NW)   /* 1444 */
#define CH (5 + NC)       /* 85 */
#define NSLICE 29         /* 29*256 = 7424 >= NA*CELLS = 7220: one cell per thread */
#define THREADS 256
#define NWAVES (THREADS / 64)
#define NBLOCKS (NSLICE * NB)

/* single-dispatch bookkeeping: device-scope atomics, self-resetting across
   graph replays (zero-initialized at module load; last block swaps back to 0). */
__device__ float g_accum = 0.0f;
__device__ int   g_cnt   = 0;

__device__ __constant__ float c_anchors[10] = {
    1.3221f, 1.73145f, 3.19275f, 4.00944f, 5.05587f,
    8.09892f, 9.47112f, 4.84053f, 11.2364f, 10.0071f};

__device__ __forceinline__ float sigmoidf_(float v) {
    return 1.0f / (1.0f + expf(-v));
}

__device__ __forceinline__ float bbox_iou_(float ax, float ay, float aw, float ah,
                                           float bx, float by, float bw, float bh) {
    float mx = fminf(ax - aw * 0.5f, bx - bw * 0.5f);
    float Mx = fmaxf(ax + aw * 0.5f, bx + bw * 0.5f);
    float my = fminf(ay - ah * 0.5f, by - bh * 0.5f);
    float My = fmaxf(ay + ah * 0.5f, by + bh * 0.5f);
    float cw = aw + bw - (Mx - mx);
    float ch = ah + bh - (My - my);
    float inter = (cw > 0.0f && ch > 0.0f) ? cw * ch : 0.0f;
    float uni = aw * ah + bw * bh - inter;
    return inter / fmaxf(uni, 1e-12f);
}

/* shared helper so the matched-cell recomputation (corr) is bit-identical to
   the owning thread's phase-B evaluation: sigmoid/exp -> pred box -> 50-record
   overlap test (iou>0.6  <=>  inter > 0.375*(area_p+area_g), division-free). */
__device__ __forceinline__ bool hit50_(float px, float py, float pw, float ph,
                                       const float4* __restrict__ sb,
                                       const float* __restrict__ st) {
    float x1 = px - pw * 0.5f, x2 = px + pw * 0.5f;
    float y1 = py - ph * 0.5f, y2 = py + ph * 0.5f;
    float pthr = 0.375f * (pw * ph);
    bool hit = false;
    #pragma unroll
    for (int u = 0; u < MAXT; ++u) {
        float4 rb = sb[u];
        float ow = fminf(x2, rb.z) - fmaxf(x1, rb.x);
        float oh = fminf(y2, rb.w) - fmaxf(y1, rb.y);
        ow = fmaxf(ow, 0.0f);
        oh = fmaxf(oh, 0.0f);
        hit = hit | (ow * oh > pthr + st[u]);
    }
    return hit;
}

// ---------------------------------------------------------------------------
// Single fused kernel. grid (NSLICE, NB) x 256.
//   wave 0: rebuilds the 50 GT records (ballot valid, shfl winner resolution)
//           into LDS — no serial scans, one barrier total for the handoff.
//   phase B: one anchor-cell per thread, division-free 50-record overlap test.
//   corr:    bx==0 block folds the matched-cell fixup into its cellsum.
//   phase C: one wave per winner record computes log-softmax class loss
//            (loads issued right after the barrier, consumed after phase B).
//   finish:  block partial -> device atomicAdd; last-arriving block writes
//            loss[0] and resets the accumulator/counter.
// ---------------------------------------------------------------------------
__global__ __launch_bounds__(THREADS) void region_fused(const float* __restrict__ out,
                                                        const float* __restrict__ tgt,
                                                        float* __restrict__ loss) {
    const int bx = blockIdx.x;
    const int b = blockIdx.y;
    const int tid = threadIdx.x;
    const int wid = tid >> 6;
    const int lane = tid & 63;

    __shared__ float4 s_box[MAXT];
    __shared__ float  s_thr[MAXT];
    __shared__ int    s_win[MAXT];
    __shared__ int    s_off[MAXT];
    __shared__ int    s_cls[MAXT];
    __shared__ float  s_wpart[NWAVES];
    __shared__ int    s_flag;

    // ---- phase-B loads: issue first (independent of everything) ----
    const int idx0 = bx * THREADS + tid;
    int idx = idx0 < NA * CELLS ? idx0 : NA * CELLS - 1;  // clamp: uniform control flow
    const int a = idx / CELLS;
    const int r = idx - a * CELLS;
    const int j = r / NW;
    const int i = r - j * NW;
    const long base = (((long)(b * NA + a)) * CH) * CELLS + r;
    const float xr = out[base];
    const float yr = out[base + CELLS];
    const float wr = out[base + 2 * CELLS];
    const float hr = out[base + 3 * CELLS];
    const float cr = out[base + 4 * CELLS];

    // ---- phase A: wave 0 builds records ----
    float gx = 0.f, gy = 0.f, gw = 0.f, gh = 0.f;
    float rxr = 0.f, ryr = 0.f, rwr = 0.f, rhr = 0.f, rcr = 0.f;
    int bn = 0, gi = 0, gj = 0;
    bool winner = false;
    if (wid == 0) {
        const bool isrec = (lane < MAXT);
        float t0 = 0.f, t1 = 0.f;
        if (isrec) {
            const float* tp = tgt + (long)b * (MAXT * 5) + lane * 5;
            t0 = tp[0];
            t1 = tp[1];
            gx = t1 * NW;
            gy = tp[2] * NH;
            gw = tp[3] * NW;
            gh = tp[4] * NH;
        }
        // valid = cumprod(t1 != 0): no zero slot at or before me
        unsigned long long nz = __ballot(isrec && (t1 != 0.0f));
        bool valid = isrec && (((~nz) & ((2ULL << lane) - 1ULL)) == 0ULL);

        // best anchor (first max wins, matching argmax)
        float best = -1.0f;
        for (int aa = 0; aa < NA; ++aa) {
            float aw = c_anchors[2 * aa], ah = c_anchors[2 * aa + 1];
            float inter = fminf(gw, aw) * fminf(gh, ah);
            float uni = gw * gh + aw * ah - inter;
            float iou = inter / fmaxf(uni, 1e-12f);
            if (iou > best) { best = iou; bn = aa; }
        }
        gi = (int)floorf(gx); gi = gi < 0 ? 0 : (gi > NW - 1 ? NW - 1 : gi);
        gj = (int)floorf(gy); gj = gj < 0 ? 0 : (gj > NH - 1 ? NH - 1 : gj);
        int key = valid ? (bn * CELLS + gj * NW + gi) : -1;

        // winner = valid and no LATER slot with the same key (shfl, no LDS scan)
        unsigned long long eq = 0ULL;
        for (int u = 0; u < MAXT; ++u) {
            int ku = __shfl(key, u);
            eq |= (unsigned long long)(ku == key) << u;
        }
        winner = valid && ((eq & ~((2ULL << lane) - 1ULL)) == 0ULL);

        float4 box;
        float thr;
        if (valid) {
            box.x = gx - gw * 0.5f; box.y = gy - gh * 0.5f;
            box.z = gx + gw * 0.5f; box.w = gy + gh * 0.5f;
            thr = 0.375f * (gw * gh);
        } else {
            box.x = box.y = box.z = box.w = 0.0f;   // degenerate: never hits
            thr = 3e38f;
        }
        if (isrec) {
            s_box[lane] = box;
            s_thr[lane] = thr;
            s_win[lane] = winner ? 1 : 0;
            int cls = (int)t0; cls = cls < 0 ? 0 : (cls > NC - 1 ? NC - 1 : cls);
            s_cls[lane] = cls;
            s_off[lane] = (bn * CH + 5) * CELLS + gj * NW + gi;
        }
        // matched-cell raw outputs for corr (bx==0 only; issued before barrier)
        if (bx == 0 && winner) {
            long rb = (((long)(b * NA + bn)) * CH) * CELLS + gj * NW + gi;
            rxr = out[rb];
            ryr = out[rb + CELLS];
            rwr = out[rb + 2 * CELLS];
            rhr = out[rb + 3 * CELLS];
            rcr = out[rb + 4 * CELLS];
        }
    }
    __syncthreads();

    // ---- phase C: issue class-loss gathers now, consume after phase B ----
    const int gwave = bx * NWAVES + wid;   // uniform per wave, 0..115
    float v0 = -INFINITY, v1 = -INFINITY, vc = 0.0f;
    bool doClass = false;
    if (gwave < MAXT && s_win[gwave]) {
        doClass = true;
        const float* cp = out + (long)b * (NA * CH * CELLS) + s_off[gwave];
        v0 = cp[(long)lane * CELLS];                              // classes 0..63
        v1 = (lane < NC - 64) ? cp[(long)(64 + lane) * CELLS] : -INFINITY;
        vc = cp[(long)s_cls[gwave] * CELLS];                      // picked class
    }

    // ---- phase B: per-cell loss ----
    const float sx = sigmoidf_(xr), sy = sigmoidf_(yr), sc = sigmoidf_(cr);
    const float px = sx + (float)i, py = sy + (float)j;
    const float pw = expf(wr) * c_anchors[2 * a];
    const float ph = expf(hr) * c_anchors[2 * a + 1];
    const bool hit = hit50_(px, py, pw, ph, s_box, s_thr);
    float dx = sx - 0.5f, dy = sy - 0.5f;
    float cellsum = 0.5f * (dx * dx + dy * dy + wr * wr + hr * hr)
                  + (hit ? 0.0f : 0.5f * sc * sc);
    if (idx0 >= NA * CELLS) cellsum = 0.0f;

    // ---- corr: matched-cell fixup, bx==0 block only, folded into cellsum ----
    if (bx == 0 && wid == 0 && winner) {
        float aw = c_anchors[2 * bn], ah = c_anchors[2 * bn + 1];
        float csx = sigmoidf_(rxr), csy = sigmoidf_(ryr), csc = sigmoidf_(rcr);
        float cpx = csx + (float)gi, cpy = csy + (float)gj;
        float cpw = expf(rwr) * aw, cph = expf(rhr) * ah;
        float iou_gt = bbox_iou_(gx, gy, gw, gh, cpx, cpy, cpw, cph);
        bool rhit = hit50_(cpx, cpy, cpw, cph, s_box, s_thr);
        float h01 = rhit ? 0.0f : 1.0f;
        float txv = gx - (float)gi, tyv = gy - (float)gj;
        float twv = logf(fmaxf(gw, 1e-12f) / aw);
        float thv = logf(fmaxf(gh, 1e-12f) / ah);
        float dsc = csc - iou_gt;
        cellsum += 0.5f * ((csx - txv) * (csx - txv) - (csx - 0.5f) * (csx - 0.5f)
                         + (csy - tyv) * (csy - tyv) - (csy - 0.5f) * (csy - 0.5f)
                         + (rwr - twv) * (rwr - twv) - rwr * rwr
                         + (rhr - thv) * (rhr - thv) - rhr * rhr)
                 + 0.5f * (5.0f * dsc * dsc - h01 * csc * csc);
    }

    // ---- phase C finish: wave log-softmax reduce ----
    float closs = 0.0f;
    if (doClass) {
        float m = fmaxf(v0, v1);
        for (int off = 32; off > 0; off >>= 1)
            m = fmaxf(m, __shfl_down(m, off));
        m = __shfl(m, 0);
        float e = expf(v0 - m) + ((lane < NC - 64) ? expf(v1 - m) : 0.0f);
        for (int off = 32; off > 0; off >>= 1)
            e += __shfl_down(e, off);
        if (lane == 0) closs = m + logf(e) - vc;
    }

    // ---- block reduce -> device accumulator; last block writes the output ----
    float v = cellsum;
    for (int off = 32; off > 0; off >>= 1) v += __shfl_down(v, off);
    if (lane == 0) s_wpart[wid] = v + closs;
    __syncthreads();
    if (tid == 0) {
        float s = 0.0f;
        for (int w = 0; w < NWAVES; ++w) s += s_wpart[w];
        atomicAdd(&g_accum, s);          // device-scope
        __threadfence();                 // my add is complete & visible
        int old = atomicAdd(&g_cnt, 1);
        s_flag = (old == NBLOCKS - 1) ? 1 : 0;
    }
    __syncthreads();
    if (s_flag) {                        // last-arriving block, all 928 adds done
        if (tid == 0) {
            __threadfence();
            loss[0] = atomicExch(&g_accum, 0.0f);   // read total + reset in one
            atomicExch(&g_cnt, 0);                  // reset for next graph replay
        }
    }
}

extern "C" void kernel_launch(void* const* d_in, const int* in_sizes, int n_in,
                              void* d_out, int out_size, void* d_ws, size_t ws_size,
                              hipStream_t stream) {
    const float* output = (const float*)d_in[0];
    const float* target = (const float*)d_in[1];
    // d_in[2] = features: unused by the reference. d_ws: unused.
    float* loss = (float*)d_out;

    dim3 grid(NSLICE, NB);
    region_fused<<<grid, THREADS, 0, stream>>>(output, target, loss);
}

// Round 4
// 179.471 us; speedup vs baseline: 1.0907x; 1.0907x over previous
//
#include <hip/hip_runtime.h>
#include <math.h>

#define NB 32
#define NA 5
#define NC 80
#define NH 38
#define NW 38
#define MAXT 50
#define CELLS (NH * NW)   /* 1444 */
#define CH (5 + NC)       /* 85 */
#define NSLICE 29         /* 29*256 = 7424 >= NA*CELLS = 7220: one cell per thread */
#define THREADS 256
#define NWAVES (THREADS / 64)

/* prep -> main handoff in module __device__ globals */
__device__ float4 g_box[NB][MAXT];   /* x1,y1,x2,y2 (degenerate if invalid) */
__device__ float  g_thr[NB][MAXT];   /* 0.375*area  (3e38 if invalid)       */
__device__ int4   g_tgt[NB][MAXT];   /* winner, cls_off, cls, pad           */
__device__ float  g_corr[NB];        /* matched-cell loss correction        */

__device__ __constant__ float c_anchors[10] = {
    1.3221f, 1.73145f, 3.19275f, 4.00944f, 5.05587f,
    8.09892f, 9.47112f, 4.84053f, 11.2364f, 10.0071f};

__device__ __forceinline__ float sigmoidf_(float v) {
    return 1.0f / (1.0f + expf(-v));
}

__device__ __forceinline__ float bbox_iou_(float ax, float ay, float aw, float ah,
                                           float bx, float by, float bw, float bh) {
    float mx = fminf(ax - aw * 0.5f, bx - bw * 0.5f);
    float Mx = fmaxf(ax + aw * 0.5f, bx + bw * 0.5f);
    float my = fminf(ay - ah * 0.5f, by - bh * 0.5f);
    float My = fmaxf(ay + ah * 0.5f, by + bh * 0.5f);
    float cw = aw + bw - (Mx - mx);
    float ch = ah + bh - (My - my);
    float inter = (cw > 0.0f && ch > 0.0f) ? cw * ch : 0.0f;
    float uni = aw * ah + bw * bh - inter;
    return inter / fmaxf(uni, 1e-12f);
}

/* shared helper so the matched-cell recomputation (corr, in prep) is
   bit-identical to the owning thread's phase-B evaluation in main:
   iou>0.6  <=>  inter > 0.375*(area_p+area_g)  — division-free. */
__device__ __forceinline__ bool hit50_(float px, float py, float pw, float ph,
                                       const float4* __restrict__ sb,
                                       const float* __restrict__ st) {
    float x1 = px - pw * 0.5f, x2 = px + pw * 0.5f;
    float y1 = py - ph * 0.5f, y2 = py + ph * 0.5f;
    float pthr = 0.375f * (pw * ph);
    bool hit = false;
    #pragma unroll
    for (int u = 0; u < MAXT; ++u) {
        float4 rb = sb[u];
        float ow = fminf(x2, rb.z) - fmaxf(x1, rb.x);
        float oh = fminf(y2, rb.w) - fmaxf(y1, rb.y);
        ow = fmaxf(ow, 0.0f);
        oh = fmaxf(oh, 0.0f);
        hit = hit | (ow * oh > pthr + st[u]);
    }
    return hit;
}

// ---------------------------------------------------------------------------
// Prep: one wave per batch (32 blocks x 64). Builds the 50 GT records,
// resolves winners with a register-only shfl loop (no serial LDS scan),
// computes the per-winner matched-cell correction
//   corr = [matched coord+conf loss] - [uniform unmatched formula]
// and zeroes the scalar loss.
// ---------------------------------------------------------------------------
__global__ __launch_bounds__(64) void region_prep(const float* __restrict__ out,
                                                  const float* __restrict__ tgt,
                                                  float* __restrict__ loss) {
    const int b = blockIdx.x;
    const int t = threadIdx.x;          // 0..63, records live in 0..49
    __shared__ float4 s_box[MAXT];
    __shared__ float  s_thr[MAXT];

    const bool isrec = (t < MAXT);
    float t0 = 0.f, t1 = 0.f, gx = 0.f, gy = 0.f, gw = 0.f, gh = 0.f;
    if (isrec) {
        const float* tp = tgt + (long)b * (MAXT * 5) + t * 5;
        t0 = tp[0];
        t1 = tp[1];
        gx = t1 * NW;
        gy = tp[2] * NH;
        gw = tp[3] * NW;
        gh = tp[4] * NH;
    }
    // valid = cumprod(t1 != 0): no zero slot at or before me
    unsigned long long nz = __ballot(isrec && (t1 != 0.0f));
    bool valid = isrec && (((~nz) & ((2ULL << t) - 1ULL)) == 0ULL);

    // best anchor (first max wins, matching argmax)
    int bn = 0;
    float best = -1.0f;
    for (int a = 0; a < NA; ++a) {
        float aw = c_anchors[2 * a], ah = c_anchors[2 * a + 1];
        float inter = fminf(gw, aw) * fminf(gh, ah);
        float uni = gw * gh + aw * ah - inter;
        float iou = inter / fmaxf(uni, 1e-12f);
        if (iou > best) { best = iou; bn = a; }
    }
    int gi = (int)floorf(gx); gi = gi < 0 ? 0 : (gi > NW - 1 ? NW - 1 : gi);
    int gj = (int)floorf(gy); gj = gj < 0 ? 0 : (gj > NH - 1 ? NH - 1 : gj);
    int key = valid ? (bn * CELLS + gj * NW + gi) : -1;

    // winner = valid and no LATER slot with the same key (register-only)
    unsigned long long eq = 0ULL;
    for (int u = 0; u < MAXT; ++u) {
        int ku = __shfl(key, u);
        eq |= (unsigned long long)(ku == key) << u;
    }
    bool winner = valid && ((eq & ~((2ULL << t) - 1ULL)) == 0ULL);

    float4 box;
    float thr;
    if (valid) {
        box.x = gx - gw * 0.5f; box.y = gy - gh * 0.5f;
        box.z = gx + gw * 0.5f; box.w = gy + gh * 0.5f;
        thr = 0.375f * (gw * gh);
    } else {
        box.x = box.y = box.z = box.w = 0.0f;   // degenerate: never hits
        thr = 3e38f;
    }
    if (isrec) {
        s_box[t] = box;
        s_thr[t] = thr;
        g_box[b][t] = box;
        g_thr[b][t] = thr;
        int cls = (int)t0; cls = cls < 0 ? 0 : (cls > NC - 1 ? NC - 1 : cls);
        int4 ti;
        ti.x = winner ? 1 : 0;
        ti.y = (bn * CH + 5) * CELLS + gj * NW + gi;   // class-channel base offset
        ti.z = cls;
        ti.w = 0;
        g_tgt[b][t] = ti;
    }
    __syncthreads();   // single wave: compiles to the needed lgkmcnt wait

    float corr = 0.0f;
    if (winner) {
        float aw = c_anchors[2 * bn], ah = c_anchors[2 * bn + 1];
        long rb = (((long)(b * NA + bn)) * CH) * CELLS + gj * NW + gi;
        float xr = out[rb];
        float yr = out[rb + CELLS];
        float wr = out[rb + 2 * CELLS];
        float hr = out[rb + 3 * CELLS];
        float cr = out[rb + 4 * CELLS];
        float sx = sigmoidf_(xr), sy = sigmoidf_(yr), sc = sigmoidf_(cr);
        float px = sx + (float)gi, py = sy + (float)gj;
        float pw = expf(wr) * aw, ph = expf(hr) * ah;
        float iou_gt = bbox_iou_(gx, gy, gw, gh, px, py, pw, ph);
        bool rhit = hit50_(px, py, pw, ph, s_box, s_thr);
        float h01 = rhit ? 0.0f : 1.0f;

        float txv = gx - (float)gi, tyv = gy - (float)gj;
        float twv = logf(fmaxf(gw, 1e-12f) / aw);
        float thv = logf(fmaxf(gh, 1e-12f) / ah);
        float dsc = sc - iou_gt;
        corr = 0.5f * ((sx - txv) * (sx - txv) - (sx - 0.5f) * (sx - 0.5f)
                     + (sy - tyv) * (sy - tyv) - (sy - 0.5f) * (sy - 0.5f)
                     + (wr - twv) * (wr - twv) - wr * wr
                     + (hr - thv) * (hr - thv) - hr * hr)
             + 0.5f * (5.0f * dsc * dsc - h01 * sc * sc);
    }
    for (int off = 32; off > 0; off >>= 1) corr += __shfl_down(corr, off);
    if (t == 0) {
        g_corr[b] = corr;
        if (b == 0) loss[0] = 0.0f;
    }
}

// ---------------------------------------------------------------------------
// Main: grid (NSLICE, NB) x 256, one anchor-cell per thread.
// Load order engineered for latency overlap:
//   (1) issue the 5 per-cell channel loads,
//   (2) stage the 50 records global->LDS (tid<50),
//   (3) read the wave-uniform class descriptor (s_load) and ISSUE the
//       scattered class-logit gathers — their ~700-cyc latency then hides
//       under (4) the 50-record VALU overlap loop,
//   (5) class log-softmax reduce, (6) block reduce, one atomicAdd per block.
// ---------------------------------------------------------------------------
__global__ __launch_bounds__(THREADS) void region_main(const float* __restrict__ out,
                                                       float* __restrict__ loss) {
    const int bx = blockIdx.x;
    const int b = blockIdx.y;
    const int tid = threadIdx.x;
    const int wid = tid >> 6;
    const int lane = tid & 63;
    __shared__ float4 s_box[MAXT];
    __shared__ float  s_thr[MAXT];
    __shared__ float  s_wpart[NWAVES];

    // (1) per-cell channel loads
    const int idx0 = bx * THREADS + tid;
    int idx = idx0 < NA * CELLS ? idx0 : NA * CELLS - 1;  // clamp: uniform control flow
    const int a = idx / CELLS;
    const int r = idx - a * CELLS;
    const int j = r / NW;
    const int i = r - j * NW;
    const long base = (((long)(b * NA + a)) * CH) * CELLS + r;
    const float xr = out[base];
    const float yr = out[base + CELLS];
    const float wr = out[base + 2 * CELLS];
    const float hr = out[base + 3 * CELLS];
    const float cr = out[base + 4 * CELLS];

    // (2) stage records
    if (tid < MAXT) {
        s_box[tid] = g_box[b][tid];
        s_thr[tid] = g_thr[b][tid];
    }

    // (3) class descriptor (wave-uniform s_load, independent of LDS staging)
    const int gwave = bx * NWAVES + wid;   // 0..115; records handled by gwave<50
    float v0 = -INFINITY, v1 = -INFINITY, vc = 0.0f;
    bool doClass = false;
    if (gwave < MAXT) {
        const int4 ti = g_tgt[b][gwave];
        if (ti.x) {
            doClass = true;
            const float* cp = out + (long)b * (NA * CH * CELLS) + ti.y;
            v0 = cp[(long)lane * CELLS];                              // classes 0..63
            v1 = (lane < NC - 64) ? cp[(long)(64 + lane) * CELLS] : -INFINITY;
            vc = cp[(long)ti.z * CELLS];                              // picked class
        }
    }

    __syncthreads();

    // (4) per-cell loss
    const float sx = sigmoidf_(xr), sy = sigmoidf_(yr), sc = sigmoidf_(cr);
    const float px = sx + (float)i, py = sy + (float)j;
    const float pw = expf(wr) * c_anchors[2 * a];
    const float ph = expf(hr) * c_anchors[2 * a + 1];
    const bool hit = hit50_(px, py, pw, ph, s_box, s_thr);
    float dx = sx - 0.5f, dy = sy - 0.5f;
    float cellsum = 0.5f * (dx * dx + dy * dy + wr * wr + hr * hr)
                  + (hit ? 0.0f : 0.5f * sc * sc);
    if (idx0 >= NA * CELLS) cellsum = 0.0f;

    // (5) class log-softmax reduce
    float closs = 0.0f;
    if (doClass) {
        float m = fmaxf(v0, v1);
        for (int off = 32; off > 0; off >>= 1)
            m = fmaxf(m, __shfl_down(m, off));
        m = __shfl(m, 0);
        float e = expf(v0 - m) + ((lane < NC - 64) ? expf(v1 - m) : 0.0f);
        for (int off = 32; off > 0; off >>= 1)
            e += __shfl_down(e, off);
        if (lane == 0) closs = m + logf(e) - vc;
    }
    // matched-cell corrections (one block per batch adds them)
    if (bx == 0 && tid == 0) closs += g_corr[b];

    // (6) block reduce -> one atomic per block
    float v = cellsum;
    for (int off = 32; off > 0; off >>= 1) v += __shfl_down(v, off);
    if (lane == 0) s_wpart[wid] = v + closs;
    __syncthreads();
    if (tid == 0) {
        float s = 0.0f;
        for (int w = 0; w < NWAVES; ++w) s += s_wpart[w];
        atomicAdd(loss, s);
    }
}

extern "C" void kernel_launch(void* const* d_in, const int* in_sizes, int n_in,
                              void* d_out, int out_size, void* d_ws, size_t ws_size,
                              hipStream_t stream) {
    const float* output = (const float*)d_in[0];
    const float* target = (const float*)d_in[1];
    // d_in[2] = features: unused by the reference. d_ws: unused.
    float* loss = (float*)d_out;

    region_prep<<<NB, 64, 0, stream>>>(output, target, loss);
    dim3 grid(NSLICE, NB);
    region_main<<<grid, THREADS, 0, stream>>>(output, loss);
}

// Round 6
// 176.004 us; speedup vs baseline: 1.1122x; 1.0197x over previous
//
#include <hip/hip_runtime.h>
#include <math.h>

#define NB 32
#define NA 5
#define NC 80
#define NH 38
#define NW 38
#define MAXT 50
#define CELLS (NH * NW)   /* 1444 */
#define CH (5 + NC)       /* 85 */
#define THREADS 256
#define NWAVES (THREADS / 64)
#define NCELLBLK 15       /* 15 blocks * 256 thr * 2 cells = 7680 >= 7220 */
#define NCLSBLK 13        /* 13 blocks * 4 waves = 52 >= 50 records */
#define NXBLK (NCELLBLK + NCLSBLK)   /* 28 */
#define NPAIRS 3610       /* 7220 / 2 */

/* prep -> main -> finish handoff in module __device__ globals */
__device__ float4 g_box[NB][MAXT];   /* x1,y1,x2,y2 (degenerate if invalid) */
__device__ float  g_thr[NB][MAXT];   /* 0.375*area  (3e38 if invalid)       */
__device__ int4   g_tgt[NB][MAXT];   /* winner, cls_off, cls, pad           */
__device__ float  g_corr[NB];        /* matched-cell loss correction        */
__device__ float  g_part[NB][NXBLK]; /* per-block partial sums (plain stores)*/

__device__ __constant__ float c_anchors[10] = {
    1.3221f, 1.73145f, 3.19275f, 4.00944f, 5.05587f,
    8.09892f, 9.47112f, 4.84053f, 11.2364f, 10.0071f};

__device__ __forceinline__ float sigmoidf_(float v) {
    return 1.0f / (1.0f + expf(-v));
}

__device__ __forceinline__ float bbox_iou_(float ax, float ay, float aw, float ah,
                                           float bx, float by, float bw, float bh) {
    float mx = fminf(ax - aw * 0.5f, bx - bw * 0.5f);
    float Mx = fmaxf(ax + aw * 0.5f, bx + bw * 0.5f);
    float my = fminf(ay - ah * 0.5f, by - bh * 0.5f);
    float My = fmaxf(ay + ah * 0.5f, by + bh * 0.5f);
    float cw = aw + bw - (Mx - mx);
    float ch = ah + bh - (My - my);
    float inter = (cw > 0.0f && ch > 0.0f) ? cw * ch : 0.0f;
    float uni = aw * ah + bw * bh - inter;
    return inter / fmaxf(uni, 1e-12f);
}

/* shared helper: matched-cell recomputation (prep) is bit-identical to the
   owning thread's evaluation (main). iou>0.6 <=> inter > 0.375*(pa+ga). */
__device__ __forceinline__ bool hit50_(float px, float py, float pw, float ph,
                                       const float4* __restrict__ sb,
                                       const float* __restrict__ st) {
    float x1 = px - pw * 0.5f, x2 = px + pw * 0.5f;
    float y1 = py - ph * 0.5f, y2 = py + ph * 0.5f;
    float pthr = 0.375f * (pw * ph);
    bool hit = false;
    #pragma unroll
    for (int u = 0; u < MAXT; ++u) {
        float4 rb = sb[u];
        float ow = fminf(x2, rb.z) - fmaxf(x1, rb.x);
        float oh = fminf(y2, rb.w) - fmaxf(y1, rb.y);
        ow = fmaxf(ow, 0.0f);
        oh = fmaxf(oh, 0.0f);
        hit = hit | (ow * oh > pthr + st[u]);
    }
    return hit;
}

/* per-cell loss given raw channel values (identical scalar sequence for both
   halves of the float2 pair) */
__device__ __forceinline__ float cell_loss_(float xr, float yr, float wr, float hr,
                                            float cr, int i, int j, int a,
                                            const float4* __restrict__ sb,
                                            const float* __restrict__ st) {
    float sx = sigmoidf_(xr), sy = sigmoidf_(yr), sc = sigmoidf_(cr);
    float px = sx + (float)i, py = sy + (float)j;
    float pw = expf(wr) * c_anchors[2 * a];
    float ph = expf(hr) * c_anchors[2 * a + 1];
    bool hit = hit50_(px, py, pw, ph, sb, st);
    float dx = sx - 0.5f, dy = sy - 0.5f;
    return 0.5f * (dx * dx + dy * dy + wr * wr + hr * hr)
         + (hit ? 0.0f : 0.5f * sc * sc);
}

// ---------------------------------------------------------------------------
// Prep: one wave per batch (32 blocks x 64). Builds the 50 GT records,
// register-only shfl winner resolution, computes the per-winner matched-cell
// correction corr = [matched loss] - [uniform unmatched formula].
// ---------------------------------------------------------------------------
__global__ __launch_bounds__(64) void region_prep(const float* __restrict__ out,
                                                  const float* __restrict__ tgt) {
    const int b = blockIdx.x;
    const int t = threadIdx.x;          // 0..63, records live in 0..49
    __shared__ float4 s_box[MAXT];
    __shared__ float  s_thr[MAXT];

    const bool isrec = (t < MAXT);
    float t0 = 0.f, t1 = 0.f, gx = 0.f, gy = 0.f, gw = 0.f, gh = 0.f;
    if (isrec) {
        const float* tp = tgt + (long)b * (MAXT * 5) + t * 5;
        t0 = tp[0];
        t1 = tp[1];
        gx = t1 * NW;
        gy = tp[2] * NH;
        gw = tp[3] * NW;
        gh = tp[4] * NH;
    }
    // valid = cumprod(t1 != 0): no zero slot at or before me
    unsigned long long nz = __ballot(isrec && (t1 != 0.0f));
    bool valid = isrec && (((~nz) & ((2ULL << t) - 1ULL)) == 0ULL);

    // best anchor (first max wins, matching argmax)
    int bn = 0;
    float best = -1.0f;
    for (int a = 0; a < NA; ++a) {
        float aw = c_anchors[2 * a], ah = c_anchors[2 * a + 1];
        float inter = fminf(gw, aw) * fminf(gh, ah);
        float uni = gw * gh + aw * ah - inter;
        float iou = inter / fmaxf(uni, 1e-12f);
        if (iou > best) { best = iou; bn = a; }
    }
    int gi = (int)floorf(gx); gi = gi < 0 ? 0 : (gi > NW - 1 ? NW - 1 : gi);
    int gj = (int)floorf(gy); gj = gj < 0 ? 0 : (gj > NH - 1 ? NH - 1 : gj);
    int key = valid ? (bn * CELLS + gj * NW + gi) : -1;

    // winner = valid and no LATER slot with the same key (register-only)
    unsigned long long eq = 0ULL;
    for (int u = 0; u < MAXT; ++u) {
        int ku = __shfl(key, u);
        eq |= (unsigned long long)(ku == key) << u;
    }
    bool winner = valid && ((eq & ~((2ULL << t) - 1ULL)) == 0ULL);

    float4 box;
    float thr;
    if (valid) {
        box.x = gx - gw * 0.5f; box.y = gy - gh * 0.5f;
        box.z = gx + gw * 0.5f; box.w = gy + gh * 0.5f;
        thr = 0.375f * (gw * gh);
    } else {
        box.x = box.y = box.z = box.w = 0.0f;   // degenerate: never hits
        thr = 3e38f;
    }
    if (isrec) {
        s_box[t] = box;
        s_thr[t] = thr;
        g_box[b][t] = box;
        g_thr[b][t] = thr;
        int cls = (int)t0; cls = cls < 0 ? 0 : (cls > NC - 1 ? NC - 1 : cls);
        int4 ti;
        ti.x = winner ? 1 : 0;
        ti.y = (bn * CH + 5) * CELLS + gj * NW + gi;   // class-channel base offset
        ti.z = cls;
        ti.w = 0;
        g_tgt[b][t] = ti;
    }
    __syncthreads();

    float corr = 0.0f;
    if (winner) {
        float aw = c_anchors[2 * bn], ah = c_anchors[2 * bn + 1];
        long rb = (((long)(b * NA + bn)) * CH) * CELLS + gj * NW + gi;
        float xr = out[rb];
        float yr = out[rb + CELLS];
        float wr = out[rb + 2 * CELLS];
        float hr = out[rb + 3 * CELLS];
        float cr = out[rb + 4 * CELLS];
        float sx = sigmoidf_(xr), sy = sigmoidf_(yr), sc = sigmoidf_(cr);
        float px = sx + (float)gi, py = sy + (float)gj;
        float pw = expf(wr) * aw, ph = expf(hr) * ah;
        float iou_gt = bbox_iou_(gx, gy, gw, gh, px, py, pw, ph);
        bool rhit = hit50_(px, py, pw, ph, s_box, s_thr);
        float h01 = rhit ? 0.0f : 1.0f;

        float txv = gx - (float)gi, tyv = gy - (float)gj;
        float twv = logf(fmaxf(gw, 1e-12f) / aw);
        float thv = logf(fmaxf(gh, 1e-12f) / ah);
        float dsc = sc - iou_gt;
        corr = 0.5f * ((sx - txv) * (sx - txv) - (sx - 0.5f) * (sx - 0.5f)
                     + (sy - tyv) * (sy - tyv) - (sy - 0.5f) * (sy - 0.5f)
                     + (wr - twv) * (wr - twv) - wr * wr
                     + (hr - thv) * (hr - thv) - hr * hr)
             + 0.5f * (5.0f * dsc * dsc - h01 * sc * sc);
    }
    for (int off = 32; off > 0; off >>= 1) corr += __shfl_down(corr, off);
    if (t == 0) g_corr[b] = corr;
}

// ---------------------------------------------------------------------------
// Main: grid (NXBLK, NB) x 256, role split at BLOCK granularity:
//   bx <  15: cell blocks — 2 cells/thread via float2 channel loads,
//             records staged in LDS, NO class work, NO atomics;
//             block partial -> plain store g_part[b][bx].
//   bx >= 15: class blocks — one wave per winner record, log-softmax,
//             no record staging; block partial -> g_part[b][bx].
// ---------------------------------------------------------------------------
__global__ __launch_bounds__(THREADS) void region_main(const float* __restrict__ out) {
    const int bx = blockIdx.x;
    const int b = blockIdx.y;
    const int tid = threadIdx.x;
    const int wid = tid >> 6;
    const int lane = tid & 63;
    __shared__ float4 s_box[MAXT];
    __shared__ float  s_thr[MAXT];
    __shared__ float  s_wpart[NWAVES];

    if (bx < NCELLBLK) {
        // ---------------- cell blocks ----------------
        const int p0 = bx * THREADS + tid;                    // pair index
        const int p = p0 < NPAIRS ? p0 : NPAIRS - 1;          // clamp (uniform flow)
        const int c0 = 2 * p;                                 // even; pair shares a,j
        const int a = c0 / CELLS;
        const int r0 = c0 - a * CELLS;
        const int j = r0 / NW;
        const int i0 = r0 - j * NW;
        const long base = (((long)(b * NA + a)) * CH) * CELLS + r0;  // 8B-aligned

        const float2 x2 = *(const float2*)&out[base];
        const float2 y2 = *(const float2*)&out[base + CELLS];
        const float2 w2 = *(const float2*)&out[base + 2 * CELLS];
        const float2 h2 = *(const float2*)&out[base + 3 * CELLS];
        const float2 q2 = *(const float2*)&out[base + 4 * CELLS];

        if (tid < MAXT) {
            s_box[tid] = g_box[b][tid];
            s_thr[tid] = g_thr[b][tid];
        }
        __syncthreads();

        float cs = cell_loss_(x2.x, y2.x, w2.x, h2.x, q2.x, i0,     j, a, s_box, s_thr)
                 + cell_loss_(x2.y, y2.y, w2.y, h2.y, q2.y, i0 + 1, j, a, s_box, s_thr);
        if (p0 >= NPAIRS) cs = 0.0f;

        for (int off = 32; off > 0; off >>= 1) cs += __shfl_down(cs, off);
        if (lane == 0) s_wpart[wid] = cs;
        __syncthreads();
        if (tid == 0) {
            float s = 0.0f;
            for (int w = 0; w < NWAVES; ++w) s += s_wpart[w];
            g_part[b][bx] = s;
        }
    } else {
        // ---------------- class blocks ----------------
        const int rec = __builtin_amdgcn_readfirstlane((bx - NCELLBLK) * NWAVES + wid); // 0..51
        float closs = 0.0f;
        if (rec < MAXT) {
            const int4 ti = g_tgt[b][rec];
            if (ti.x) {
                const float* cp = out + (long)b * (NA * CH * CELLS) + ti.y;
                float v0 = cp[(long)lane * CELLS];                              // classes 0..63
                float v1 = (lane < NC - 64) ? cp[(long)(64 + lane) * CELLS] : -INFINITY;
                float vc = cp[(long)ti.z * CELLS];                              // picked class
                float m = fmaxf(v0, v1);
                for (int off = 32; off > 0; off >>= 1)
                    m = fmaxf(m, __shfl_down(m, off));
                m = __shfl(m, 0);
                float e = expf(v0 - m) + ((lane < NC - 64) ? expf(v1 - m) : 0.0f);
                for (int off = 32; off > 0; off >>= 1)
                    e += __shfl_down(e, off);
                if (lane == 0) closs = m + logf(e) - vc;
            }
        }
        if (lane == 0) s_wpart[wid] = closs;
        __syncthreads();
        if (tid == 0) {
            float s = 0.0f;
            for (int w = 0; w < NWAVES; ++w) s += s_wpart[w];
            g_part[b][bx] = s;
        }
    }
}

// ---------------------------------------------------------------------------
// Finish: one block sums 896 block partials + 32 corrections -> loss[0].
// (No atomics anywhere in the pipeline; no separate zero pass needed.)
// ---------------------------------------------------------------------------
__global__ __launch_bounds__(1024) void region_finish(float* __restrict__ loss) {
    const int tid = threadIdx.x;
    const int wid = tid >> 6;
    const int lane = tid & 63;
    __shared__ float sp[16];

    float v = 0.0f;
    if (tid < NB * NXBLK) v = ((const float*)g_part)[tid];
    if (tid < NB) v += g_corr[tid];

    for (int off = 32; off > 0; off >>= 1) v += __shfl_down(v, off);
    if (lane == 0) sp[wid] = v;
    __syncthreads();
    if (tid == 0) {
        float s = 0.0f;
        for (int w = 0; w < 16; ++w) s += sp[w];
        loss[0] = s;
    }
}

extern "C" void kernel_launch(void* const* d_in, const int* in_sizes, int n_in,
                              void* d_out, int out_size, void* d_ws, size_t ws_size,
                              hipStream_t stream) {
    const float* output = (const float*)d_in[0];
    const float* target = (const float*)d_in[1];
    // d_in[2] = features: unused by the reference. d_ws: unused.
    float* loss = (float*)d_out;

    region_prep<<<NB, 64, 0, stream>>>(output, target);
    dim3 grid(NXBLK, NB);
    region_main<<<grid, THREADS, 0, stream>>>(output);
    region_finish<<<1, 1024, 0, stream>>>(loss);
}

// Round 7
// 167.068 us; speedup vs baseline: 1.1717x; 1.0535x over previous
//
#include <hip/hip_runtime.h>
#include <math.h>

#define NB 32
#define NA 5
#define NC 80
#define NH 38
#define NW 38
#define MAXT 50
#define CELLS (NH * NW)   /* 1444 */
#define CH (5 + NC)       /* 85 */
#define THREADS 256
#define NWAVES (THREADS / 64)
#define NCELLBLK 15       /* 15 blocks * 256 thr * 2 cells = 7680 >= 7220 */
#define NCLSBLK 13        /* 13 blocks * 4 waves = 52 >= 50 records */
#define NXBLK (NCELLBLK + NCLSBLK)   /* 28 */
#define NPAIRS 3610       /* 7220 / 2 */

/* main -> finish handoff: per-block partial sums (plain stores, no atomics) */
__device__ float g_part[NB][NXBLK];

__device__ __constant__ float c_anchors[10] = {
    1.3221f, 1.73145f, 3.19275f, 4.00944f, 5.05587f,
    8.09892f, 9.47112f, 4.84053f, 11.2364f, 10.0071f};

__device__ __forceinline__ float sigmoidf_(float v) {
    return 1.0f / (1.0f + expf(-v));
}

__device__ __forceinline__ float bbox_iou_(float ax, float ay, float aw, float ah,
                                           float bx, float by, float bw, float bh) {
    float mx = fminf(ax - aw * 0.5f, bx - bw * 0.5f);
    float Mx = fmaxf(ax + aw * 0.5f, bx + bw * 0.5f);
    float my = fminf(ay - ah * 0.5f, by - bh * 0.5f);
    float My = fmaxf(ay + ah * 0.5f, by + bh * 0.5f);
    float cw = aw + bw - (Mx - mx);
    float ch = ah + bh - (My - my);
    float inter = (cw > 0.0f && ch > 0.0f) ? cw * ch : 0.0f;
    float uni = aw * ah + bw * bh - inter;
    return inter / fmaxf(uni, 1e-12f);
}

/* hit test: iou>0.6 <=> inter > 0.375*(area_p+area_g), division-free.
   Cell path evaluates all 50 sequentially; class path evaluates the SAME
   per-record expression on lane u + ballot-OR -> bit-identical boolean. */
__device__ __forceinline__ bool hit50_(float px, float py, float pw, float ph,
                                       const float4* __restrict__ sb,
                                       const float* __restrict__ st) {
    float x1 = px - pw * 0.5f, x2 = px + pw * 0.5f;
    float y1 = py - ph * 0.5f, y2 = py + ph * 0.5f;
    float pthr = 0.375f * (pw * ph);
    bool hit = false;
    #pragma unroll
    for (int u = 0; u < MAXT; ++u) {
        float4 rb = sb[u];
        float ow = fminf(x2, rb.z) - fmaxf(x1, rb.x);
        float oh = fminf(y2, rb.w) - fmaxf(y1, rb.y);
        ow = fmaxf(ow, 0.0f);
        oh = fmaxf(oh, 0.0f);
        hit = hit | (ow * oh > pthr + st[u]);
    }
    return hit;
}

/* per-cell loss given raw channel values */
__device__ __forceinline__ float cell_loss_(float xr, float yr, float wr, float hr,
                                            float cr, int i, int j, int a,
                                            const float4* __restrict__ sb,
                                            const float* __restrict__ st) {
    float sx = sigmoidf_(xr), sy = sigmoidf_(yr), sc = sigmoidf_(cr);
    float px = sx + (float)i, py = sy + (float)j;
    float pw = expf(wr) * c_anchors[2 * a];
    float ph = expf(hr) * c_anchors[2 * a + 1];
    bool hit = hit50_(px, py, pw, ph, sb, st);
    float dx = sx - 0.5f, dy = sy - 0.5f;
    return 0.5f * (dx * dx + dy * dy + wr * wr + hr * hr)
         + (hit ? 0.0f : 0.5f * sc * sc);
}

// ---------------------------------------------------------------------------
// Single main kernel, grid (NXBLK, NB) x 256, block-granularity role split.
// Every block's wave 0 rebuilds the 50 GT boxes/thresholds from the 1KB
// target record (ballot valid, ~30 VALU — hides under the block's own
// global loads; no prep kernel, no serialization).
//   bx <  15 (cell blocks): 2 cells/thread float2 loads; 50-record overlap
//       loop; no winner resolution, no class work, no atomics.
//   bx >= 15 (class blocks): wave 0 additionally resolves winners (register
//       shfl loop) + record metadata -> LDS; then each wave owns one record:
//       class log-softmax + the matched-cell correction
//       corr = [matched loss] - [uniform unmatched formula]
//       (hit test distributed lane-per-record + ballot, bit-identical).
// Each block stores its partial to g_part[b][bx]; finish kernel sums 896.
// ---------------------------------------------------------------------------
__global__ __launch_bounds__(THREADS) void region_main(const float* __restrict__ out,
                                                       const float* __restrict__ tgt) {
    const int bx = blockIdx.x;
    const int b = blockIdx.y;
    const int tid = threadIdx.x;
    const int wid = tid >> 6;
    const int lane = tid & 63;
    const bool isClass = (bx >= NCELLBLK);

    __shared__ float4 s_box[MAXT];
    __shared__ float  s_thr[MAXT];
    __shared__ int    s_win[MAXT];
    __shared__ int    s_off[MAXT];
    __shared__ int    s_cls[MAXT];
    __shared__ float  s_gx[MAXT], s_gy[MAXT], s_gw[MAXT], s_gh[MAXT];
    __shared__ int    s_bn[MAXT], s_gi[MAXT], s_gj[MAXT];
    __shared__ float  s_wpart[NWAVES];

    // ---- cell blocks: issue the 10 channel dwords FIRST (latency overlap) ----
    float2 x2, y2, w2, h2, q2;
    int a = 0, j = 0, i0 = 0, p0 = 0;
    if (!isClass) {
        p0 = bx * THREADS + tid;                              // pair index
        int p = p0 < NPAIRS ? p0 : NPAIRS - 1;                // clamp (uniform flow)
        int c0 = 2 * p;                                       // even; pair shares a,j
        a = c0 / CELLS;
        int r0 = c0 - a * CELLS;
        j = r0 / NW;
        i0 = r0 - j * NW;
        const long base = (((long)(b * NA + a)) * CH) * CELLS + r0;  // 8B-aligned
        x2 = *(const float2*)&out[base];
        y2 = *(const float2*)&out[base + CELLS];
        w2 = *(const float2*)&out[base + 2 * CELLS];
        h2 = *(const float2*)&out[base + 3 * CELLS];
        q2 = *(const float2*)&out[base + 4 * CELLS];
    }

    // ---- wave 0: build records (both roles); class blocks also resolve winners ----
    if (wid == 0) {
        const bool isrec = (lane < MAXT);
        float t0 = 0.f, t1 = 0.f, gx = 0.f, gy = 0.f, gw = 0.f, gh = 0.f;
        if (isrec) {
            const float* tp = tgt + (long)b * (MAXT * 5) + lane * 5;
            t0 = tp[0];
            t1 = tp[1];
            gx = t1 * NW;
            gy = tp[2] * NH;
            gw = tp[3] * NW;
            gh = tp[4] * NH;
        }
        // valid = cumprod(t1 != 0): no zero slot at or before me
        unsigned long long nz = __ballot(isrec && (t1 != 0.0f));
        bool valid = isrec && (((~nz) & ((2ULL << lane) - 1ULL)) == 0ULL);

        float4 box;
        float thr;
        if (valid) {
            box.x = gx - gw * 0.5f; box.y = gy - gh * 0.5f;
            box.z = gx + gw * 0.5f; box.w = gy + gh * 0.5f;
            thr = 0.375f * (gw * gh);
        } else {
            box.x = box.y = box.z = box.w = 0.0f;   // degenerate: never hits
            thr = 3e38f;
        }
        if (isrec) {
            s_box[lane] = box;
            s_thr[lane] = thr;
        }

        if (isClass) {
            // best anchor (first max wins, matching argmax)
            int bn = 0;
            float best = -1.0f;
            for (int aa = 0; aa < NA; ++aa) {
                float aw = c_anchors[2 * aa], ah = c_anchors[2 * aa + 1];
                float inter = fminf(gw, aw) * fminf(gh, ah);
                float uni = gw * gh + aw * ah - inter;
                float iou = inter / fmaxf(uni, 1e-12f);
                if (iou > best) { best = iou; bn = aa; }
            }
            int gi = (int)floorf(gx); gi = gi < 0 ? 0 : (gi > NW - 1 ? NW - 1 : gi);
            int gj = (int)floorf(gy); gj = gj < 0 ? 0 : (gj > NH - 1 ? NH - 1 : gj);
            int key = valid ? (bn * CELLS + gj * NW + gi) : -1;

            // winner = valid and no LATER slot with the same key (register-only)
            unsigned long long eq = 0ULL;
            for (int u = 0; u < MAXT; ++u) {
                int ku = __shfl(key, u);
                eq |= (unsigned long long)(ku == key) << u;
            }
            bool winner = valid && ((eq & ~((2ULL << lane) - 1ULL)) == 0ULL);

            if (isrec) {
                s_win[lane] = winner ? 1 : 0;
                int cls = (int)t0; cls = cls < 0 ? 0 : (cls > NC - 1 ? NC - 1 : cls);
                s_cls[lane] = cls;
                s_off[lane] = (bn * CH + 5) * CELLS + gj * NW + gi;
                s_gx[lane] = gx; s_gy[lane] = gy; s_gw[lane] = gw; s_gh[lane] = gh;
                s_bn[lane] = bn; s_gi[lane] = gi; s_gj[lane] = gj;
            }
        }
    }
    __syncthreads();

    if (!isClass) {
        // ---------------- cell blocks ----------------
        float cs = cell_loss_(x2.x, y2.x, w2.x, h2.x, q2.x, i0,     j, a, s_box, s_thr)
                 + cell_loss_(x2.y, y2.y, w2.y, h2.y, q2.y, i0 + 1, j, a, s_box, s_thr);
        if (p0 >= NPAIRS) cs = 0.0f;

        for (int off = 32; off > 0; off >>= 1) cs += __shfl_down(cs, off);
        if (lane == 0) s_wpart[wid] = cs;
    } else {
        // ---------------- class blocks: one wave per record ----------------
        const int rec = __builtin_amdgcn_readfirstlane((bx - NCELLBLK) * NWAVES + wid); // 0..51
        float closs = 0.0f;
        if (rec < MAXT && s_win[rec]) {
            const int off_c = s_off[rec];
            const int cls = s_cls[rec];
            const float* cp = out + (long)b * (NA * CH * CELLS) + off_c;
            // class log-softmax (81 strided lines, one per lane)
            float v0 = cp[(long)lane * CELLS];                              // classes 0..63
            float v1 = (lane < NC - 64) ? cp[(long)(64 + lane) * CELLS] : -INFINITY;
            float vc = cp[(long)cls * CELLS];                               // picked class
            float m = fmaxf(v0, v1);
            for (int off = 32; off > 0; off >>= 1)
                m = fmaxf(m, __shfl_down(m, off));
            m = __shfl(m, 0);
            float e = expf(v0 - m) + ((lane < NC - 64) ? expf(v1 - m) : 0.0f);
            for (int off = 32; off > 0; off >>= 1)
                e += __shfl_down(e, off);

            // matched-cell correction (wave-uniform broadcast loads)
            float gx = s_gx[rec], gy = s_gy[rec], gw = s_gw[rec], gh = s_gh[rec];
            int bn = s_bn[rec], gi = s_gi[rec], gj = s_gj[rec];
            float aw = c_anchors[2 * bn], ah = c_anchors[2 * bn + 1];
            long rb = (((long)(b * NA + bn)) * CH) * CELLS + gj * NW + gi;
            float xr = out[rb];
            float yr = out[rb + CELLS];
            float wr = out[rb + 2 * CELLS];
            float hr = out[rb + 3 * CELLS];
            float cr = out[rb + 4 * CELLS];
            float sx = sigmoidf_(xr), sy = sigmoidf_(yr), sc = sigmoidf_(cr);
            float px = sx + (float)gi, py = sy + (float)gj;
            float pw = expf(wr) * aw, ph = expf(hr) * ah;
            float iou_gt = bbox_iou_(gx, gy, gw, gh, px, py, pw, ph);

            // hit test distributed: lane u evaluates record u (same expression
            // as hit50_'s term u -> bit-identical), OR via ballot
            float x1 = px - pw * 0.5f, xx2 = px + pw * 0.5f;
            float y1 = py - ph * 0.5f, yy2 = py + ph * 0.5f;
            float pthr = 0.375f * (pw * ph);
            bool myhit = false;
            if (lane < MAXT) {
                float4 rbx = s_box[lane];
                float ow = fminf(xx2, rbx.z) - fmaxf(x1, rbx.x);
                float oh = fminf(yy2, rbx.w) - fmaxf(y1, rbx.y);
                ow = fmaxf(ow, 0.0f);
                oh = fmaxf(oh, 0.0f);
                myhit = (ow * oh > pthr + s_thr[lane]);
            }
            bool rhit = (__ballot(myhit) != 0ULL);
            float h01 = rhit ? 0.0f : 1.0f;

            if (lane == 0) {
                float txv = gx - (float)gi, tyv = gy - (float)gj;
                float twv = logf(fmaxf(gw, 1e-12f) / aw);
                float thv = logf(fmaxf(gh, 1e-12f) / ah);
                float dsc = sc - iou_gt;
                float corr = 0.5f * ((sx - txv) * (sx - txv) - (sx - 0.5f) * (sx - 0.5f)
                                   + (sy - tyv) * (sy - tyv) - (sy - 0.5f) * (sy - 0.5f)
                                   + (wr - twv) * (wr - twv) - wr * wr
                                   + (hr - thv) * (hr - thv) - hr * hr)
                           + 0.5f * (5.0f * dsc * dsc - h01 * sc * sc);
                closs = (m + logf(e) - vc) + corr;
            }
        }
        if (lane == 0) s_wpart[wid] = closs;
    }

    __syncthreads();
    if (tid == 0) {
        float s = 0.0f;
        for (int w = 0; w < NWAVES; ++w) s += s_wpart[w];
        g_part[b][bx] = s;
    }
}

// ---------------------------------------------------------------------------
// Finish: one block sums the 896 block partials -> loss[0]. No atomics.
// ---------------------------------------------------------------------------
__global__ __launch_bounds__(1024) void region_finish(float* __restrict__ loss) {
    const int tid = threadIdx.x;
    const int wid = tid >> 6;
    const int lane = tid & 63;
    __shared__ float sp[16];

    float v = 0.0f;
    if (tid < NB * NXBLK) v = ((const float*)g_part)[tid];

    for (int off = 32; off > 0; off >>= 1) v += __shfl_down(v, off);
    if (lane == 0) sp[wid] = v;
    __syncthreads();
    if (tid == 0) {
        float s = 0.0f;
        for (int w = 0; w < 16; ++w) s += sp[w];
        loss[0] = s;
    }
}

extern "C" void kernel_launch(void* const* d_in, const int* in_sizes, int n_in,
                              void* d_out, int out_size, void* d_ws, size_t ws_size,
                              hipStream_t stream) {
    const float* output = (const float*)d_in[0];
    const float* target = (const float*)d_in[1];
    // d_in[2] = features: unused by the reference. d_ws: unused.
    float* loss = (float*)d_out;

    dim3 grid(NXBLK, NB);
    region_main<<<grid, THREADS, 0, stream>>>(output, target);
    region_finish<<<1, 1024, 0, stream>>>(loss);
}